// Round 12
// baseline (166.828 us; speedup 1.0000x reference)
//
#include <hip/hip_runtime.h>

#define DIM 128

typedef float    v4f __attribute__((ext_vector_type(4)));
typedef _Float16 h8  __attribute__((ext_vector_type(8)));
typedef _Float16 h4  __attribute__((ext_vector_type(4)));

// ---------------- prep: x(f32) -> slice-major fp16 ----------------
// 4 slices of 32 features; slice k is a contiguous N*32-element block
// (3.2 MB @ N=50k) so it fits a 4 MiB per-XCD L2.
__global__ __launch_bounds__(256) void cvt_sliced_kernel(const float* __restrict__ x,
                                                         _Float16* __restrict__ xsl,
                                                         long long N, long long total8) {
    long long i = (long long)blockIdx.x * blockDim.x + threadIdx.x;
    if (i >= total8) return;
    long long r = i >> 4;      // row
    int o = (int)(i & 15);     // feature octet 0..15
    v4f f0 = *reinterpret_cast<const v4f*>(x + i * 8);
    v4f f1 = *reinterpret_cast<const v4f*>(x + i * 8 + 4);
    h8 v;
    v[0] = (_Float16)f0.x; v[1] = (_Float16)f0.y;
    v[2] = (_Float16)f0.z; v[3] = (_Float16)f0.w;
    v[4] = (_Float16)f1.x; v[5] = (_Float16)f1.y;
    v[6] = (_Float16)f1.z; v[7] = (_Float16)f1.w;
    int k = o >> 2;            // slice 0..3
    int q = o & 3;             // octet within slice
    __builtin_nontemporal_store(v,
        reinterpret_cast<h8*>(xsl + (size_t)k * N * 32 + r * 32 + q * 8));
}

// ---------------- fused pass A: edge diff + hyper partial sums ----------------
// slice k = blockIdx&3 for BOTH roles (blockIdx round-robins XCDs, 8%4==0 ->
// XCD x sees only slice x&3 -> slice stays L2-resident).
// EDGE role: 8 lanes per edge-slice; each lane loads 4 fp16 features (8 B) and
//   stores ONE dense v4f (16 B). A/B vs R11: stores are NORMAL (cached) --
//   touch-once write stream should self-evict in L2 while the constantly
//   re-referenced slice stays MRU; tests whether the nt bypass path was
//   limiting write throughput.
// HYPER role: 4 lanes per hyperedge, 2 per thread, partial s11/s22/s12 to fp16 P.
__global__ __launch_bounds__(256) void fusedA_kernel(
    const _Float16* __restrict__ xsl,
    const int* __restrict__ ei,
    const int* __restrict__ hi,
    float* __restrict__ out_edge,
    _Float16* __restrict__ P,
    int E, int H, long long N, int CE, int C) {

    int b = blockIdx.x;
    int k = b & 3;
    long long c = (long long)(b >> 2);
    long long eBefore = (c * CE) / C;
    long long eAfter  = ((c + 1) * CE) / C;

    int t = threadIdx.x;
    const _Float16* base = xsl + (size_t)k * N * 32;

    if (eAfter > eBefore) {
        // ---------------- edge chunk: 64 edges, 2 per thread ----------------
        int unit = t >> 3;     // 32 units per block
        int sub  = t & 7;      // 8 lanes per unit
        long long ebase = eBefore * 64 + unit;
        long long eA = ebase;
        long long eB = ebase + 32;
        if (eA > (long long)E - 1) eA = (long long)E - 1;
        if (eB > (long long)E - 1) eB = (long long)E - 1;

        int sA = ei[eA];
        int dA = ei[(size_t)E + eA];
        int sB = ei[eB];
        int dB = ei[(size_t)E + eB];

        h4 hsA = *reinterpret_cast<const h4*>(base + (size_t)sA * 32 + sub * 4);
        h4 hdA = *reinterpret_cast<const h4*>(base + (size_t)dA * 32 + sub * 4);
        h4 hsB = *reinterpret_cast<const h4*>(base + (size_t)sB * 32 + sub * 4);
        h4 hdB = *reinterpret_cast<const h4*>(base + (size_t)dB * 32 + sub * 4);

        v4f rA, rB;
        rA.x = (float)hsA[0] - (float)hdA[0];
        rA.y = (float)hsA[1] - (float)hdA[1];
        rA.z = (float)hsA[2] - (float)hdA[2];
        rA.w = (float)hsA[3] - (float)hdA[3];
        rB.x = (float)hsB[0] - (float)hdB[0];
        rB.y = (float)hsB[1] - (float)hdB[1];
        rB.z = (float)hsB[2] - (float)hdB[2];
        rB.w = (float)hsB[3] - (float)hdB[3];

        *reinterpret_cast<v4f*>(out_edge + (size_t)eA * DIM + k * 32 + sub * 4) = rA;
        *reinterpret_cast<v4f*>(out_edge + (size_t)eB * DIM + k * 32 + sub * 4) = rB;
    } else {
        // ---------------- hyper chunk: 128 hyperedges, 2 per thread ----------------
        int unit = t >> 2;     // 64 units per block
        int sub  = t & 3;      // 4 lanes per unit
        long long hc = c - eBefore;
        long long hbase = hc * 128 + unit;
        long long hA = hbase;
        long long hB = hbase + 64;
        if (hA > (long long)H - 1) hA = (long long)H - 1;
        if (hB > (long long)H - 1) hB = (long long)H - 1;

        int iaA = hi[hA];
        int ibA = hi[(size_t)H + hA];
        int icA = hi[2 * (size_t)H + hA];
        int iaB = hi[hB];
        int ibB = hi[(size_t)H + hB];
        int icB = hi[2 * (size_t)H + hB];

        h8 haA = *reinterpret_cast<const h8*>(base + (size_t)iaA * 32 + sub * 8);
        h8 hbA = *reinterpret_cast<const h8*>(base + (size_t)ibA * 32 + sub * 8);
        h8 hcA = *reinterpret_cast<const h8*>(base + (size_t)icA * 32 + sub * 8);
        h8 haB = *reinterpret_cast<const h8*>(base + (size_t)iaB * 32 + sub * 8);
        h8 hbB = *reinterpret_cast<const h8*>(base + (size_t)ibB * 32 + sub * 8);
        h8 hcB = *reinterpret_cast<const h8*>(base + (size_t)icB * 32 + sub * 8);

        float s11A = 0.f, s22A = 0.f, s12A = 0.f;
        float s11B = 0.f, s22B = 0.f, s12B = 0.f;
#pragma unroll
        for (int q = 0; q < 8; ++q) {
            float v01 = (float)haA[q] - (float)hbA[q];
            float v02 = (float)haA[q] - (float)hcA[q];
            s11A = fmaf(v01, v01, s11A);
            s22A = fmaf(v02, v02, s22A);
            s12A = fmaf(v01, v02, s12A);
            float w01 = (float)haB[q] - (float)hbB[q];
            float w02 = (float)haB[q] - (float)hcB[q];
            s11B = fmaf(w01, w01, s11B);
            s22B = fmaf(w02, w02, s22B);
            s12B = fmaf(w01, w02, s12B);
        }
        // reduce across the 4-lane unit
        s11A += __shfl_xor(s11A, 1); s11A += __shfl_xor(s11A, 2);
        s22A += __shfl_xor(s22A, 1); s22A += __shfl_xor(s22A, 2);
        s12A += __shfl_xor(s12A, 1); s12A += __shfl_xor(s12A, 2);
        s11B += __shfl_xor(s11B, 1); s11B += __shfl_xor(s11B, 2);
        s22B += __shfl_xor(s22B, 1); s22B += __shfl_xor(s22B, 2);
        s12B += __shfl_xor(s12B, 1); s12B += __shfl_xor(s12B, 2);

        if (sub < 3) {
            float vA = (sub == 0) ? s11A : (sub == 1) ? s22A : s12A;
            float vB = (sub == 0) ? s11B : (sub == 1) ? s22B : s12B;
            __builtin_nontemporal_store((_Float16)vA,
                P + ((size_t)sub * 4 + k) * H + hA);
            __builtin_nontemporal_store((_Float16)vB,
                P + ((size_t)sub * 4 + k) * H + hB);
        }
    }
}

// ---------------- pass B: combine slice partials -> cosines ----------------
__global__ __launch_bounds__(256) void hyperB_kernel(
    const _Float16* __restrict__ P,
    float* __restrict__ out_hyper,
    int H) {
    long long h = (long long)blockIdx.x * blockDim.x + threadIdx.x;
    if (h >= H) return;
    float s11 = 0.f, s22 = 0.f, s12 = 0.f;
#pragma unroll
    for (int k = 0; k < 4; ++k) {
        s11 += (float)P[((size_t)0 * 4 + k) * H + h];
        s22 += (float)P[((size_t)1 * 4 + k) * H + h];
        s12 += (float)P[((size_t)2 * 4 + k) * H + h];
    }
    float s33 = s11 + s22 - 2.f * s12;   // |v12|^2, v12 = v02 - v01
    float n01 = sqrtf(s11);
    float n02 = sqrtf(s22);
    float n12 = sqrtf(s33);
    float* po = out_hyper + (size_t)h * 3;
    __builtin_nontemporal_store(s12 / (n01 * n02), po);
    __builtin_nontemporal_store((s11 - s12) / (n01 * n12), po + 1);
    __builtin_nontemporal_store((s22 - s12) / (n12 * n02), po + 2);
}

// ---------------- fallback: fused f32 straight from x ----------------
__global__ __launch_bounds__(256) void fused_f32_kernel(
    const float* __restrict__ x,
    const int* __restrict__ ei,
    const int* __restrict__ hi,
    float* __restrict__ out_edge,
    float* __restrict__ out_hyper,
    int E, int H, int nEB, int T) {

    long long b = blockIdx.x;
    long long aBefore = (b * (long long)nEB) / T;
    long long aAfter  = ((b + 1) * (long long)nEB) / T;
    int t   = threadIdx.x;
    int grp = t >> 4;
    int sub = t & 15;
    int c0  = sub * 4;
    int c1  = c0 + 64;

    if (aAfter > aBefore) {
        long long e = aBefore * 16 + grp;
        if (e >= E) return;
        int s = ei[e];
        int d = ei[(size_t)E + e];
        const float* xs = x + (size_t)s * DIM;
        const float* xd = x + (size_t)d * DIM;
        v4f s0 = *reinterpret_cast<const v4f*>(xs + c0);
        v4f s1 = *reinterpret_cast<const v4f*>(xs + c1);
        v4f d0 = *reinterpret_cast<const v4f*>(xd + c0);
        v4f d1 = *reinterpret_cast<const v4f*>(xd + c1);
        v4f r0 = s0 - d0;
        v4f r1 = s1 - d1;
        float* po = out_edge + (size_t)e * DIM;
        __builtin_nontemporal_store(r0, reinterpret_cast<v4f*>(po + c0));
        __builtin_nontemporal_store(r1, reinterpret_cast<v4f*>(po + c1));
    } else {
        long long hb = b - aBefore;
        long long h  = hb * 16 + grp;
        if (h >= H) return;
        int ia = hi[h];
        int ib = hi[(size_t)H + h];
        int ic = hi[2 * (size_t)H + h];
        const float* pa = x + (size_t)ia * DIM;
        const float* pb = x + (size_t)ib * DIM;
        const float* pc = x + (size_t)ic * DIM;
        v4f a0 = *reinterpret_cast<const v4f*>(pa + c0);
        v4f a1 = *reinterpret_cast<const v4f*>(pa + c1);
        v4f b0 = *reinterpret_cast<const v4f*>(pb + c0);
        v4f b1 = *reinterpret_cast<const v4f*>(pb + c1);
        v4f q0 = *reinterpret_cast<const v4f*>(pc + c0);
        v4f q1 = *reinterpret_cast<const v4f*>(pc + c1);
        float s11 = 0.f, s22 = 0.f, s12 = 0.f;
#define ACC(A, B, C) { float v01 = (A) - (B); float v02 = (A) - (C); \
        s11 = fmaf(v01, v01, s11); s22 = fmaf(v02, v02, s22); s12 = fmaf(v01, v02, s12); }
        ACC(a0.x, b0.x, q0.x) ACC(a0.y, b0.y, q0.y) ACC(a0.z, b0.z, q0.z) ACC(a0.w, b0.w, q0.w)
        ACC(a1.x, b1.x, q1.x) ACC(a1.y, b1.y, q1.y) ACC(a1.z, b1.z, q1.z) ACC(a1.w, b1.w, q1.w)
#undef ACC
#pragma unroll
        for (int m = 1; m < 16; m <<= 1) {
            s11 += __shfl_xor(s11, m);
            s22 += __shfl_xor(s22, m);
            s12 += __shfl_xor(s12, m);
        }
        if (sub == 0) {
            float s33 = s11 + s22 - 2.f * s12;
            float n01 = sqrtf(s11);
            float n02 = sqrtf(s22);
            float n12 = sqrtf(s33);
            float* po = out_hyper + (size_t)h * 3;
            po[0] = s12 / (n01 * n02);
            po[1] = (s11 - s12) / (n01 * n12);
            po[2] = (s22 - s12) / (n12 * n02);
        }
    }
}

extern "C" void kernel_launch(void* const* d_in, const int* in_sizes, int n_in,
                              void* d_out, int out_size, void* d_ws, size_t ws_size,
                              hipStream_t stream) {
    const float* x  = (const float*)d_in[0];
    const int*   ei = (const int*)d_in[1];   // (2, E)
    const int*   hi = (const int*)d_in[2];   // (3, H)

    const long long ND = (long long)in_sizes[0];   // N * D
    const long long N  = ND / DIM;
    const int E = in_sizes[1] / 2;
    const int H = in_sizes[2] / 3;

    float* out_edge  = (float*)d_out;                  // (E, D)
    float* out_hyper = out_edge + (size_t)E * DIM;     // (H, 3)

    const size_t need = (size_t)ND * sizeof(_Float16)            // sliced fp16 x
                      + (size_t)12 * H * sizeof(_Float16) + 64;  // fp16 partials
    if (ws_size >= need) {
        _Float16* xsl = (_Float16*)d_ws;
        // 16-byte align the partials
        size_t off = ((size_t)ND * sizeof(_Float16) + 15) & ~(size_t)15;
        _Float16* P = (_Float16*)((char*)d_ws + off);

        {
            long long total8 = ND / 8;
            long long grid = (total8 + 255) / 256;
            cvt_sliced_kernel<<<(dim3)(unsigned)grid, 256, 0, stream>>>(x, xsl, N, total8);
        }
        {
            int CE = (E + 63) / 64;                // edge chunks (64 edges each)
            int CH = (H + 127) / 128;              // hyper chunks (128 each)
            int C  = CE + CH;
            long long grid = (long long)C * 4;     // x4 slices
            fusedA_kernel<<<(dim3)(unsigned)grid, 256, 0, stream>>>(
                xsl, ei, hi, out_edge, P, E, H, N, CE, C);
        }
        {
            long long grid = ((long long)H + 255) / 256;
            hyperB_kernel<<<(dim3)(unsigned)grid, 256, 0, stream>>>(P, out_hyper, H);
        }
    } else {
        int nEB = (E + 15) / 16;
        int nHB = (H + 15) / 16;
        int T   = nEB + nHB;
        fused_f32_kernel<<<T, 256, 0, stream>>>(x, ei, hi, out_edge, out_hyper, E, H, nEB, T);
    }
}

// Round 13
// 102.700 us; speedup vs baseline: 1.6244x; 1.6244x over previous
//
#include <hip/hip_runtime.h>

#define DIM 128

typedef float    v4f __attribute__((ext_vector_type(4)));
typedef _Float16 h8  __attribute__((ext_vector_type(8)));
typedef _Float16 h4  __attribute__((ext_vector_type(4)));

// ---------------- prep: x(f32) -> slice-major fp16 ----------------
// 4 slices of 32 features; slice k is a contiguous N*32-element block
// (3.2 MB @ N=50k) so it fits a 4 MiB per-XCD L2.
__global__ __launch_bounds__(256) void cvt_sliced_kernel(const float* __restrict__ x,
                                                         _Float16* __restrict__ xsl,
                                                         long long N, long long total8) {
    long long i = (long long)blockIdx.x * blockDim.x + threadIdx.x;
    if (i >= total8) return;
    long long r = i >> 4;      // row
    int o = (int)(i & 15);     // feature octet 0..15
    v4f f0 = *reinterpret_cast<const v4f*>(x + i * 8);
    v4f f1 = *reinterpret_cast<const v4f*>(x + i * 8 + 4);
    h8 v;
    v[0] = (_Float16)f0.x; v[1] = (_Float16)f0.y;
    v[2] = (_Float16)f0.z; v[3] = (_Float16)f0.w;
    v[4] = (_Float16)f1.x; v[5] = (_Float16)f1.y;
    v[6] = (_Float16)f1.z; v[7] = (_Float16)f1.w;
    int k = o >> 2;            // slice 0..3
    int q = o & 3;             // octet within slice
    __builtin_nontemporal_store(v,
        reinterpret_cast<h8*>(xsl + (size_t)k * N * 32 + r * 32 + q * 8));
}

// ---------------- fused pass A: edge diff + hyper partial sums ----------------
// slice k = blockIdx&3 for BOTH roles (blockIdx round-robins XCDs, 8%4==0 ->
// XCD x sees only slice x&3 -> slice stays L2-resident).
// EDGE role: 8 lanes per edge-slice; each lane loads 4 fp16 features (8 B) and
//   nt-stores ONE dense v4f (16 B) -> per-instruction contiguous 128 B/unit.
//   NT is load-bearing (R12: cached stores evict the pinned slice, 103->167us).
// HYPER role: 4 lanes per hyperedge, 2 per thread, partial s11/s22/s12 to fp16 P.
__global__ __launch_bounds__(256) void fusedA_kernel(
    const _Float16* __restrict__ xsl,
    const int* __restrict__ ei,
    const int* __restrict__ hi,
    float* __restrict__ out_edge,
    _Float16* __restrict__ P,
    int E, int H, long long N, int CE, int C) {

    int b = blockIdx.x;
    int k = b & 3;
    long long c = (long long)(b >> 2);
    long long eBefore = (c * CE) / C;
    long long eAfter  = ((c + 1) * CE) / C;

    int t = threadIdx.x;
    const _Float16* base = xsl + (size_t)k * N * 32;

    if (eAfter > eBefore) {
        // ---------------- edge chunk: 64 edges, 2 per thread ----------------
        int unit = t >> 3;     // 32 units per block
        int sub  = t & 7;      // 8 lanes per unit
        long long ebase = eBefore * 64 + unit;
        long long eA = ebase;
        long long eB = ebase + 32;
        if (eA > (long long)E - 1) eA = (long long)E - 1;
        if (eB > (long long)E - 1) eB = (long long)E - 1;

        int sA = ei[eA];
        int dA = ei[(size_t)E + eA];
        int sB = ei[eB];
        int dB = ei[(size_t)E + eB];

        h4 hsA = *reinterpret_cast<const h4*>(base + (size_t)sA * 32 + sub * 4);
        h4 hdA = *reinterpret_cast<const h4*>(base + (size_t)dA * 32 + sub * 4);
        h4 hsB = *reinterpret_cast<const h4*>(base + (size_t)sB * 32 + sub * 4);
        h4 hdB = *reinterpret_cast<const h4*>(base + (size_t)dB * 32 + sub * 4);

        v4f rA, rB;
        rA.x = (float)hsA[0] - (float)hdA[0];
        rA.y = (float)hsA[1] - (float)hdA[1];
        rA.z = (float)hsA[2] - (float)hdA[2];
        rA.w = (float)hsA[3] - (float)hdA[3];
        rB.x = (float)hsB[0] - (float)hdB[0];
        rB.y = (float)hsB[1] - (float)hdB[1];
        rB.z = (float)hsB[2] - (float)hdB[2];
        rB.w = (float)hsB[3] - (float)hdB[3];

        __builtin_nontemporal_store(rA,
            reinterpret_cast<v4f*>(out_edge + (size_t)eA * DIM + k * 32 + sub * 4));
        __builtin_nontemporal_store(rB,
            reinterpret_cast<v4f*>(out_edge + (size_t)eB * DIM + k * 32 + sub * 4));
    } else {
        // ---------------- hyper chunk: 128 hyperedges, 2 per thread ----------------
        int unit = t >> 2;     // 64 units per block
        int sub  = t & 3;      // 4 lanes per unit
        long long hc = c - eBefore;
        long long hbase = hc * 128 + unit;
        long long hA = hbase;
        long long hB = hbase + 64;
        if (hA > (long long)H - 1) hA = (long long)H - 1;
        if (hB > (long long)H - 1) hB = (long long)H - 1;

        int iaA = hi[hA];
        int ibA = hi[(size_t)H + hA];
        int icA = hi[2 * (size_t)H + hA];
        int iaB = hi[hB];
        int ibB = hi[(size_t)H + hB];
        int icB = hi[2 * (size_t)H + hB];

        h8 haA = *reinterpret_cast<const h8*>(base + (size_t)iaA * 32 + sub * 8);
        h8 hbA = *reinterpret_cast<const h8*>(base + (size_t)ibA * 32 + sub * 8);
        h8 hcA = *reinterpret_cast<const h8*>(base + (size_t)icA * 32 + sub * 8);
        h8 haB = *reinterpret_cast<const h8*>(base + (size_t)iaB * 32 + sub * 8);
        h8 hbB = *reinterpret_cast<const h8*>(base + (size_t)ibB * 32 + sub * 8);
        h8 hcB = *reinterpret_cast<const h8*>(base + (size_t)icB * 32 + sub * 8);

        float s11A = 0.f, s22A = 0.f, s12A = 0.f;
        float s11B = 0.f, s22B = 0.f, s12B = 0.f;
#pragma unroll
        for (int q = 0; q < 8; ++q) {
            float v01 = (float)haA[q] - (float)hbA[q];
            float v02 = (float)haA[q] - (float)hcA[q];
            s11A = fmaf(v01, v01, s11A);
            s22A = fmaf(v02, v02, s22A);
            s12A = fmaf(v01, v02, s12A);
            float w01 = (float)haB[q] - (float)hbB[q];
            float w02 = (float)haB[q] - (float)hcB[q];
            s11B = fmaf(w01, w01, s11B);
            s22B = fmaf(w02, w02, s22B);
            s12B = fmaf(w01, w02, s12B);
        }
        // reduce across the 4-lane unit
        s11A += __shfl_xor(s11A, 1); s11A += __shfl_xor(s11A, 2);
        s22A += __shfl_xor(s22A, 1); s22A += __shfl_xor(s22A, 2);
        s12A += __shfl_xor(s12A, 1); s12A += __shfl_xor(s12A, 2);
        s11B += __shfl_xor(s11B, 1); s11B += __shfl_xor(s11B, 2);
        s22B += __shfl_xor(s22B, 1); s22B += __shfl_xor(s22B, 2);
        s12B += __shfl_xor(s12B, 1); s12B += __shfl_xor(s12B, 2);

        if (sub < 3) {
            float vA = (sub == 0) ? s11A : (sub == 1) ? s22A : s12A;
            float vB = (sub == 0) ? s11B : (sub == 1) ? s22B : s12B;
            __builtin_nontemporal_store((_Float16)vA,
                P + ((size_t)sub * 4 + k) * H + hA);
            __builtin_nontemporal_store((_Float16)vB,
                P + ((size_t)sub * 4 + k) * H + hB);
        }
    }
}

// ---------------- pass B: combine slice partials -> cosines ----------------
__global__ __launch_bounds__(256) void hyperB_kernel(
    const _Float16* __restrict__ P,
    float* __restrict__ out_hyper,
    int H) {
    long long h = (long long)blockIdx.x * blockDim.x + threadIdx.x;
    if (h >= H) return;
    float s11 = 0.f, s22 = 0.f, s12 = 0.f;
#pragma unroll
    for (int k = 0; k < 4; ++k) {
        s11 += (float)P[((size_t)0 * 4 + k) * H + h];
        s22 += (float)P[((size_t)1 * 4 + k) * H + h];
        s12 += (float)P[((size_t)2 * 4 + k) * H + h];
    }
    float s33 = s11 + s22 - 2.f * s12;   // |v12|^2, v12 = v02 - v01
    float n01 = sqrtf(s11);
    float n02 = sqrtf(s22);
    float n12 = sqrtf(s33);
    float* po = out_hyper + (size_t)h * 3;
    __builtin_nontemporal_store(s12 / (n01 * n02), po);
    __builtin_nontemporal_store((s11 - s12) / (n01 * n12), po + 1);
    __builtin_nontemporal_store((s22 - s12) / (n12 * n02), po + 2);
}

// ---------------- fallback: fused f32 straight from x ----------------
__global__ __launch_bounds__(256) void fused_f32_kernel(
    const float* __restrict__ x,
    const int* __restrict__ ei,
    const int* __restrict__ hi,
    float* __restrict__ out_edge,
    float* __restrict__ out_hyper,
    int E, int H, int nEB, int T) {

    long long b = blockIdx.x;
    long long aBefore = (b * (long long)nEB) / T;
    long long aAfter  = ((b + 1) * (long long)nEB) / T;
    int t   = threadIdx.x;
    int grp = t >> 4;
    int sub = t & 15;
    int c0  = sub * 4;
    int c1  = c0 + 64;

    if (aAfter > aBefore) {
        long long e = aBefore * 16 + grp;
        if (e >= E) return;
        int s = ei[e];
        int d = ei[(size_t)E + e];
        const float* xs = x + (size_t)s * DIM;
        const float* xd = x + (size_t)d * DIM;
        v4f s0 = *reinterpret_cast<const v4f*>(xs + c0);
        v4f s1 = *reinterpret_cast<const v4f*>(xs + c1);
        v4f d0 = *reinterpret_cast<const v4f*>(xd + c0);
        v4f d1 = *reinterpret_cast<const v4f*>(xd + c1);
        v4f r0 = s0 - d0;
        v4f r1 = s1 - d1;
        float* po = out_edge + (size_t)e * DIM;
        __builtin_nontemporal_store(r0, reinterpret_cast<v4f*>(po + c0));
        __builtin_nontemporal_store(r1, reinterpret_cast<v4f*>(po + c1));
    } else {
        long long hb = b - aBefore;
        long long h  = hb * 16 + grp;
        if (h >= H) return;
        int ia = hi[h];
        int ib = hi[(size_t)H + h];
        int ic = hi[2 * (size_t)H + h];
        const float* pa = x + (size_t)ia * DIM;
        const float* pb = x + (size_t)ib * DIM;
        const float* pc = x + (size_t)ic * DIM;
        v4f a0 = *reinterpret_cast<const v4f*>(pa + c0);
        v4f a1 = *reinterpret_cast<const v4f*>(pa + c1);
        v4f b0 = *reinterpret_cast<const v4f*>(pb + c0);
        v4f b1 = *reinterpret_cast<const v4f*>(pb + c1);
        v4f q0 = *reinterpret_cast<const v4f*>(pc + c0);
        v4f q1 = *reinterpret_cast<const v4f*>(pc + c1);
        float s11 = 0.f, s22 = 0.f, s12 = 0.f;
#define ACC(A, B, C) { float v01 = (A) - (B); float v02 = (A) - (C); \
        s11 = fmaf(v01, v01, s11); s22 = fmaf(v02, v02, s22); s12 = fmaf(v01, v02, s12); }
        ACC(a0.x, b0.x, q0.x) ACC(a0.y, b0.y, q0.y) ACC(a0.z, b0.z, q0.z) ACC(a0.w, b0.w, q0.w)
        ACC(a1.x, b1.x, q1.x) ACC(a1.y, b1.y, q1.y) ACC(a1.z, b1.z, q1.z) ACC(a1.w, b1.w, q1.w)
#undef ACC
#pragma unroll
        for (int m = 1; m < 16; m <<= 1) {
            s11 += __shfl_xor(s11, m);
            s22 += __shfl_xor(s22, m);
            s12 += __shfl_xor(s12, m);
        }
        if (sub == 0) {
            float s33 = s11 + s22 - 2.f * s12;
            float n01 = sqrtf(s11);
            float n02 = sqrtf(s22);
            float n12 = sqrtf(s33);
            float* po = out_hyper + (size_t)h * 3;
            po[0] = s12 / (n01 * n02);
            po[1] = (s11 - s12) / (n01 * n12);
            po[2] = (s22 - s12) / (n12 * n02);
        }
    }
}

extern "C" void kernel_launch(void* const* d_in, const int* in_sizes, int n_in,
                              void* d_out, int out_size, void* d_ws, size_t ws_size,
                              hipStream_t stream) {
    const float* x  = (const float*)d_in[0];
    const int*   ei = (const int*)d_in[1];   // (2, E)
    const int*   hi = (const int*)d_in[2];   // (3, H)

    const long long ND = (long long)in_sizes[0];   // N * D
    const long long N  = ND / DIM;
    const int E = in_sizes[1] / 2;
    const int H = in_sizes[2] / 3;

    float* out_edge  = (float*)d_out;                  // (E, D)
    float* out_hyper = out_edge + (size_t)E * DIM;     // (H, 3)

    const size_t need = (size_t)ND * sizeof(_Float16)            // sliced fp16 x
                      + (size_t)12 * H * sizeof(_Float16) + 64;  // fp16 partials
    if (ws_size >= need) {
        _Float16* xsl = (_Float16*)d_ws;
        // 16-byte align the partials
        size_t off = ((size_t)ND * sizeof(_Float16) + 15) & ~(size_t)15;
        _Float16* P = (_Float16*)((char*)d_ws + off);

        {
            long long total8 = ND / 8;
            long long grid = (total8 + 255) / 256;
            cvt_sliced_kernel<<<(dim3)(unsigned)grid, 256, 0, stream>>>(x, xsl, N, total8);
        }
        {
            int CE = (E + 63) / 64;                // edge chunks (64 edges each)
            int CH = (H + 127) / 128;              // hyper chunks (128 each)
            int C  = CE + CH;
            long long grid = (long long)C * 4;     // x4 slices
            fusedA_kernel<<<(dim3)(unsigned)grid, 256, 0, stream>>>(
                xsl, ei, hi, out_edge, P, E, H, N, CE, C);
        }
        {
            long long grid = ((long long)H + 255) / 256;
            hyperB_kernel<<<(dim3)(unsigned)grid, 256, 0, stream>>>(P, out_hyper, H);
        }
    } else {
        int nEB = (E + 15) / 16;
        int nHB = (H + 15) / 16;
        int T   = nEB + nHB;
        fused_f32_kernel<<<T, 256, 0, stream>>>(x, ei, hi, out_edge, out_hyper, E, H, nEB, T);
    }
}